// Round 9
// baseline (643.679 us; speedup 1.0000x reference)
//
#include <hip/hip_runtime.h>
#include <math.h>

// ---- geometry constants (match reference) ----
#define NA   24
#define NU   128
#define NV   64
#define NW   128   // volume W (x)
#define NH   128   // volume H (y)
#define ND   64    // volume D (z)
#define NS   128   // samples per ray
#define F_STEP 1.5625f            // 2*HS/S = 200/128
#define F_DL  (200.0f / 127.0f)   // linspace(156,356,128) spacing
#define F_L0  156.0f
#define INV_DL (127.0f / 200.0f)

#define NRAYS (NA * NV * NU)      // 196608
#define VOX   (NW * NH * ND)      // 1048576

typedef float v2f __attribute__((ext_vector_type(2)));

// cos/sin(k*15 deg), double-rounded-to-float (diff vs cosf(f32 angle) ~1ulp;
// residual impact ~1e-5 << 0.525 threshold)
__device__ __constant__ float CSA[NA] = {
    1.0f,  0.96592582628906829f,  0.86602540378443865f,  0.70710678118654752f,
    0.5f,  0.25881904510252076f,  0.0f,                 -0.25881904510252076f,
   -0.5f, -0.70710678118654752f, -0.86602540378443865f, -0.96592582628906829f,
   -1.0f, -0.96592582628906829f, -0.86602540378443865f, -0.70710678118654752f,
   -0.5f, -0.25881904510252076f,  0.0f,                  0.25881904510252076f,
    0.5f,  0.70710678118654752f,  0.86602540378443865f,  0.96592582628906829f
};
__device__ __constant__ float SNA[NA] = {
    0.0f,  0.25881904510252076f,  0.5f,                  0.70710678118654752f,
    0.86602540378443865f,  0.96592582628906829f,  1.0f,  0.96592582628906829f,
    0.86602540378443865f,  0.70710678118654752f,  0.5f,  0.25881904510252076f,
    0.0f, -0.25881904510252076f, -0.5f,                 -0.70710678118654752f,
   -0.86602540378443865f, -0.96592582628906829f, -1.0f, -0.96592582628906829f,
   -0.86602540378443865f, -0.70710678118654752f, -0.5f, -0.25881904510252076f
};

// Per-ray geometry for FP.
__device__ __forceinline__ void ray_setup(int a, int v, int u,
                                          float& sx, float& sy,
                                          float& dx, float& dy, float& dz) {
    float ang = (float)((double)a * (15.0 * M_PI / 180.0));
    float c = cosf(ang), s = sinf(ang);
    float uu = (float)u - 63.5f;
    float vv = (float)v - 31.5f;
    float ux = 512.0f * c - uu * s;
    float uy = 512.0f * s + uu * c;
    float uz = vv;
    float invn = 1.0f / sqrtf(ux * ux + uy * uy + uz * uz);
    dx = ux * invn; dy = uy * invn; dz = uz * invn;
    sx = -256.0f * c; sy = -256.0f * s;
}

// ---------------- forward projection, segmented over ell ----------------
__global__ __launch_bounds__(256) void fp_seg_kernel(const float* __restrict__ vol,
                                                     float* __restrict__ part) {
    int r = blockIdx.x * blockDim.x + threadIdx.x;
    int seg = blockIdx.y;
    int u = r & (NU - 1);
    int v = (r >> 7) & (NV - 1);
    int a = r >> 13;

    float sx, sy, dx, dy, dz;
    ray_setup(a, v, u, sx, sy, dx, dy, dz);

    float rx = 1.0f / dx, ry = 1.0f / dy, rz = 1.0f / dz;
    float ex0 = (-64.55f - sx) * rx, ex1 = (64.55f - sx) * rx;
    float ey0 = (-64.55f - sy) * ry, ey1 = (64.55f - sy) * ry;
    float ez0 = (-32.55f) * rz,      ez1 = (32.55f) * rz;
    float llo = fmaxf(fmaxf(fminf(ex0, ex1), fminf(ey0, ey1)), fminf(ez0, ez1));
    float lhi = fminf(fminf(fmaxf(ex0, ex1), fmaxf(ey0, ey1)), fmaxf(ez0, ez1));
    int i_lo = max(seg * 64,      (int)ceilf((llo - F_L0) * INV_DL));
    int i_hi = min(seg * 64 + 63, (int)floorf((lhi - F_L0) * INV_DL));

    float acc = 0.0f;
    for (int i = i_lo; i <= i_hi; ++i) {
        float ell = F_L0 + F_DL * (float)i;
        float cx = sx + ell * dx + 63.5f;
        float cy = sy + ell * dy + 63.5f;
        float cz =      ell * dz + 31.5f;
        float fx = floorf(cx), fy = floorf(cy), fz = floorf(cz);
        int ix = (int)fx, iy = (int)fy, iz = (int)fz;
        float wx1 = cx - fx, wy1 = cy - fy, wz1 = cz - fz;
        float wx0 = 1.0f - wx1, wy0 = 1.0f - wy1, wz0 = 1.0f - wz1;
        bool bx0 = (unsigned)ix < NW,      bx1 = (unsigned)(ix + 1) < NW;
        bool by0 = (unsigned)iy < NH,      by1 = (unsigned)(iy + 1) < NH;
        bool bz0 = (unsigned)iz < ND,      bz1 = (unsigned)(iz + 1) < ND;
        long base = ((long)iz * NH + iy) * NW + ix;
        float v000 = (bz0 && by0 && bx0) ? vol[base]                 : 0.0f;
        float v001 = (bz0 && by0 && bx1) ? vol[base + 1]             : 0.0f;
        float v010 = (bz0 && by1 && bx0) ? vol[base + NW]            : 0.0f;
        float v011 = (bz0 && by1 && bx1) ? vol[base + NW + 1]        : 0.0f;
        float v100 = (bz1 && by0 && bx0) ? vol[base + NH * NW]       : 0.0f;
        float v101 = (bz1 && by0 && bx1) ? vol[base + NH * NW + 1]   : 0.0f;
        float v110 = (bz1 && by1 && bx0) ? vol[base + NH * NW + NW]  : 0.0f;
        float v111 = (bz1 && by1 && bx1) ? vol[base + NH * NW + NW + 1] : 0.0f;
        acc += wz0 * (wy0 * (wx0 * v000 + wx1 * v001) +
                      wy1 * (wx0 * v010 + wx1 * v011)) +
               wz1 * (wy0 * (wx0 * v100 + wx1 * v101) +
                      wy1 * (wx0 * v110 + wx1 * v111));
    }
    part[seg * NRAYS + r] = acc;
}

// ------- residual + cosine weight + Ram-Lak along u; writes TRANSPOSED resT[a][u][v] -------
__global__ __launch_bounds__(NU) void ramp_kernel(const float* __restrict__ part,
                                                  const float* __restrict__ p,
                                                  float* __restrict__ resT) {
    __shared__ float row[NU];
    int rowid = blockIdx.x;          // a*NV + v
    int u = threadIdx.x;
    int e = rowid * NU + u;
    int a = rowid >> 6;
    int v = rowid & (NV - 1);
    float sino = (part[e] + part[NRAYS + e]) * F_STEP;
    double du = (double)u - 64.0;
    double dv = (double)v - 32.0;
    float cw = (float)(512.0 / sqrt(262144.0 + dv * dv + du * du));
    row[u] = (sino - p[e]) * cw;
    __syncthreads();
    float acc = 0.125f * row[u];
#pragma unroll
    for (int d = 1; d <= 63; d += 2) {
        float f = (float)(-0.5 / (M_PI * M_PI * (double)(d * d)));
        float lo = (u - d >= 0) ? row[u - d] : 0.0f;
        float hi = (u + d < NU) ? row[u + d] : 0.0f;
        acc += f * (lo + hi);
    }
    resT[(a << 13) + (u << 6) + v] = acc;   // [a][u][v]
}

// ---------------- back projection: lanes = v, slab-free, no LDS staging ----------------
// Wave = one xy-column, lane = v. Support of every u lies in t in [tvlo,tvhi]
// (c*(t*pu-Vx)+s*(t*qu-Vy) = 512t-rho), whose ell-width <= 2.86 < 2*DL -> the same
// 2-candidate enumeration as R8 works directly from tvlo: NO per-u slab test.
// resT[a][u][v] gives one coalesced 256B wave-load per u-iter (L1/L2-resident);
// no barriers until the final writeout sync. Trig from __constant__ (s_load).
__global__ __launch_bounds__(512, 8) void bp_gather7(const float* __restrict__ resT,
                                                     float* __restrict__ out) {
    __shared__ float s_acc[8 * 64];       // per-wave z-accumulator columns

    const int tid  = threadIdx.x;
    const int lane = tid & 63;            // = v
    const int wv   = tid >> 6;            // wave 0..7
    const int y    = blockIdx.x >> 4;     // 0..127
    const int x16  = blockIdx.x & 15;     // 0..15
    const int xi   = x16 * 8 + wv;        // 8 consecutive x per block

    const float x0 = (float)xi - 63.5f;
    const float y0 = (float)y  - 63.5f;
    const float vvf = (float)lane - 31.5f;
    const float s2  = fmaf(vvf, vvf, 262144.0f);   // vv^2 + 512^2
    const v2f vv2   = {vvf, vvf};
    const v2f one2  = {1.0f, 1.0f}, zero2 = {0.0f, 0.0f};
    const float cK  = -(F_L0 * INV_DL) - 1.0e-3f;

    s_acc[tid] = 0.0f;

    for (int a = 0; a < NA; ++a) {
        const float c  = CSA[a];
        const float sn = SNA[a];
        const float c512 = 512.0f * c;
        const float s512 = 512.0f * sn;
        const float ab1  = fabsf(c) + fabsf(sn);

        const float Vx  = x0 + 256.0f * c;
        const float Vy  = y0 + 256.0f * sn;
        const float rho = fmaf(x0, c, fmaf(y0, sn, 256.0f));   // in [166, 346]
        const float tvlo = (rho - ab1) * (1.0f / 512.0f);
        const float tvhi = (rho + ab1) * (1.0f / 512.0f);
        // u-window (per-wave)
        const float yp = y0 * c - x0 * sn;
        const float rlo = __builtin_amdgcn_rcpf(rho - ab1);
        const float rhi = __builtin_amdgcn_rcpf(rho + ab1);
        const float A = yp - ab1, B = yp + ab1;
        const float uumin = 512.0f * A * ((A >= 0.0f) ? rhi : rlo);
        const float uumax = 512.0f * B * ((B >= 0.0f) ? rlo : rhi);
        const int u_lo = max(0,   (int)ceilf(uumin + 63.49f));
        const int u_hi = min(127, (int)floorf(uumax + 63.51f));
        if (u_lo > u_hi) continue;

        // static z-bin base: nonzero deposits have t in [tvlo,tvhi] -> fz spans <=0.18
        const float tloM = tvlo - 1.0e-3f;
        const float thiM = tvhi + 1.0e-3f;
        const float Zmin = fmaf(vvf, (vvf >= 0.0f) ? tloM : thiM, 31.5f);
        const float izbf = floorf(Zmin);       // in [8, 53] (cone reach, no clamp)
        const int   izb  = (int)izbf;
        const v2f b0 = {izbf, izbf};
        const float tDL = tvlo * INV_DL;

        v2f D0 = zero2, D1 = zero2, D2 = zero2, D3 = zero2;
        const v2f mVx = {-Vx, -Vx}, mVy = {-Vy, -Vy};

        const float* ru = resT + (a << 13) + (u_lo << 6) + lane;
        float uuf = (float)u_lo - 63.5f;
        for (int u = u_lo; u <= u_hi; ++u, uuf += 1.0f, ru += 64) {
            const float rv = *ru;                          // coalesced 256B/wave
            const float pu = fmaf(-uuf, sn, c512);
            const float qu = fmaf(uuf, c, s512);
            const float arg  = fmaf(uuf, uuf, s2);
            const float invn = __builtin_amdgcn_rsqf(arg);
            const float nn   = arg * invn;                 // sqrt(arg)
            const float i0f  = ceilf(fmaf(tDL, nn, cK));
            const float ell0 = fmaf(i0f, F_DL, F_L0);
            v2f tp;
            tp.x = ell0 * invn;
            tp.y = fmaf(F_DL, invn, tp.x);
            const v2f pu2 = {pu, pu}, qu2 = {qu, qu};
            v2f wx = __builtin_elementwise_max(
                one2 - __builtin_elementwise_abs(__builtin_elementwise_fma(tp, pu2, mVx)), zero2);
            v2f wy = __builtin_elementwise_max(
                one2 - __builtin_elementwise_abs(__builtin_elementwise_fma(tp, qu2, mVy)), zero2);
            v2f val = wx * wy;
            const v2f rv2 = {rv, rv};
            val = val * rv2;
            const v2f fz2 = __builtin_elementwise_fma(tp, vv2, (v2f){31.5f, 31.5f});
            const v2f g = fz2 - b0;
            D0 = __builtin_elementwise_fma(__builtin_elementwise_max(
                     one2 - __builtin_elementwise_abs(g), zero2), val, D0);
            D1 = __builtin_elementwise_fma(__builtin_elementwise_max(
                     one2 - __builtin_elementwise_abs(g - one2), zero2), val, D1);
            D2 = __builtin_elementwise_fma(__builtin_elementwise_max(
                     one2 - __builtin_elementwise_abs(g - (v2f){2.0f, 2.0f}), zero2), val, D2);
            D3 = __builtin_elementwise_fma(__builtin_elementwise_max(
                     one2 - __builtin_elementwise_abs(g - (v2f){3.0f, 3.0f}), zero2), val, D3);
        }

        float* accw = s_acc + (wv << 6);       // wave-private column
        atomicAdd(&accw[izb],     D0.x + D0.y);
        atomicAdd(&accw[izb + 1], D1.x + D1.y);
        atomicAdd(&accw[izb + 2], D2.x + D2.y);
        atomicAdd(&accw[izb + 3], D3.x + D3.y);
    }
    __syncthreads();

    // writeout: 8 consecutive x per 8 lanes -> 32B chunks
    const int z  = tid >> 3;
    const int w8 = tid & 7;
    out[(z << 14) + (y << 7) + x16 * 8 + w8] = s_acc[(w8 << 6) + z] * F_STEP;
}

extern "C" void kernel_launch(void* const* d_in, const int* in_sizes, int n_in,
                              void* d_out, int out_size, void* d_ws, size_t ws_size,
                              hipStream_t stream) {
    const float* x = (const float*)d_in[0];   // [1,1,64,128,128]
    const float* p = (const float*)d_in[1];   // [1,1,24,64,128]
    float* out  = (float*)d_out;              // [1,1,64,128,128]
    float* resT = (float*)d_ws;               // transposed filtered residual, NRAYS floats
    float* part = resT + NRAYS;               // 2 FP segments, 2*NRAYS floats

    dim3 fpg(NRAYS / 256, 2);
    fp_seg_kernel<<<fpg, 256, 0, stream>>>(x, part);
    ramp_kernel<<<NA * NV, NU, 0, stream>>>(part, p, resT);
    bp_gather7<<<16 * 128, 512, 0, stream>>>(resT, out);
}